// Round 1
// 443.888 us; speedup vs baseline: 1.0293x; 1.0293x over previous
//
#include <hip/hip_runtime.h>
#include <hip/hip_bf16.h>

#define N_NODES 8192
#define D_IN    512
#define H       256
#define D_OUT   16
#define K_CL    16
#define MAXN    96

// flat output element offsets (dtype-agnostic): output | Z_1 | Z_0 | score
#define OUT_OFF 0
#define Z1_OFF  131072
#define Z0_OFF  262144
#define SC_OFF  2359296

typedef unsigned int   u32;
typedef unsigned short u16;
typedef __attribute__((ext_vector_type(8))) short bf16x8;
typedef __attribute__((ext_vector_type(4))) float f32x4;

__device__ __forceinline__ float load_in(const void* p, int bf, size_t idx) {
    if (bf) { u32 w = ((const u16*)p)[idx]; return __uint_as_float(w << 16); }
    return ((const float*)p)[idx];
}
__device__ __forceinline__ void store_out(void* p, int bf, size_t idx, float v) {
    if (bf) ((__hip_bfloat16*)p)[idx] = __float2bfloat16(v);
    else    ((float*)p)[idx] = v;
}

// bf16 {0,1} arrays contain u32 word 0x00003F80 (pair (1.0, 0.0));
// fp32 {0.0f,1.0f} arrays contain only 0x00000000 / 0x3F800000.
__global__ void k_detect(const u32* __restrict__ adjw, int* __restrict__ flag) {
    int t = blockIdx.x * 256 + threadIdx.x;           // 65536 threads
    int hit = 0;
    #pragma unroll 4
    for (int i = 0; i < 16; i++)
        if (adjw[(size_t)t + (size_t)i * 65536] == 0x00003F80u) hit = 1;
    if (hit) atomicOr(flag, 1);
}

__global__ void k_prep_small(const void* av, const void* C_a, const void* Wgcn,
                             const int* __restrict__ flag,
                             float* a_f, float* Ca_f, float* Wg_f) {
    int bf = *flag;
    int i = blockIdx.x * 256 + threadIdx.x;
    if (i < 512)        a_f[i]         = load_in(av,   bf, i);
    else if (i < 4608)  Ca_f[i - 512]  = load_in(C_a,  bf, i - 512);
    else if (i < 8704)  Wg_f[i - 4608] = load_in(Wgcn, bf, i - 4608);
}

// Build W^T as bf16 [H][D_IN] so MFMA B-fragments are contiguous 16B loads.
// Coalesced writes (k contiguous per thread), scattered-but-cached reads.
__global__ void k_prep_wt(const void* __restrict__ wraw,
                          const int* __restrict__ flag, u16* __restrict__ Wt) {
    int bf = *flag;
    int idx = blockIdx.x * 256 + threadIdx.x;         // 131072
    int h = idx >> 9, k = idx & 511;
    float v = load_in(wraw, bf, (size_t)k * H + h);
    __hip_bfloat16 b = __float2bfloat16(v);
    Wt[(size_t)h * D_IN + k] = *(u16*)&b;
}

__global__ __launch_bounds__(256) void k_gemm_wh(
    const void* __restrict__ xraw, const void* __restrict__ wraw,
    const u16* __restrict__ Wt,
    const int* __restrict__ flag, float* __restrict__ Wh)
{
    int bf = *flag;
    __shared__ float xs[32][68];
    __shared__ float ws_[32][68];
    int tid = threadIdx.x;
    int bm = blockIdx.x >> 2, bn = blockIdx.x & 3;
    int m0 = bm * 64, n0 = bn * 64;

    if (bf) {
        // ---- bf16 MFMA path: 64x64 tile, 4 waves, each wave 32x32 ----
        int wave = tid >> 6, lane = tid & 63;
        int wr = wave >> 1, wc = wave & 1;
        int r0 = m0 + wr * 32, c0 = n0 + wc * 32;
        int lr = lane & 15, lk = lane >> 4;           // row-in-16, k-chunk
        const u16* xp = (const u16*)xraw;
        // A: lane holds A[r0+16i+lr][k0 + lk*8 + 0..8)  (row-major x, contiguous)
        // B: lane holds W[k0+lk*8+0..8)][c0+16j+lr] = Wt[c0+16j+lr][k0+lk*8..] (contiguous)
        const u16* a0p = xp + (size_t)(r0 + lr)      * D_IN + lk * 8;
        const u16* a1p = xp + (size_t)(r0 + 16 + lr) * D_IN + lk * 8;
        const u16* b0p = Wt + (size_t)(c0 + lr)      * D_IN + lk * 8;
        const u16* b1p = Wt + (size_t)(c0 + 16 + lr) * D_IN + lk * 8;
        f32x4 acc[2][2] = {};
        #pragma unroll 4
        for (int k0 = 0; k0 < D_IN; k0 += 32) {
            bf16x8 a0 = *(const bf16x8*)(a0p + k0);
            bf16x8 a1 = *(const bf16x8*)(a1p + k0);
            bf16x8 b0 = *(const bf16x8*)(b0p + k0);
            bf16x8 b1 = *(const bf16x8*)(b1p + k0);
            acc[0][0] = __builtin_amdgcn_mfma_f32_16x16x32_bf16(a0, b0, acc[0][0], 0, 0, 0);
            acc[0][1] = __builtin_amdgcn_mfma_f32_16x16x32_bf16(a0, b1, acc[0][1], 0, 0, 0);
            acc[1][0] = __builtin_amdgcn_mfma_f32_16x16x32_bf16(a1, b0, acc[1][0], 0, 0, 0);
            acc[1][1] = __builtin_amdgcn_mfma_f32_16x16x32_bf16(a1, b1, acc[1][1], 0, 0, 0);
        }
        // C/D layout (m89-verified): col = c0+16j+(lane&15), row = r0+16i+4*(lane>>4)+reg
        #pragma unroll
        for (int i = 0; i < 2; i++) {
            #pragma unroll
            for (int reg = 0; reg < 4; reg++) {
                int r = r0 + 16 * i + 4 * lk + reg;
                Wh[(size_t)r * H + c0 + lr]      = acc[i][0][reg];
                Wh[(size_t)r * H + c0 + 16 + lr] = acc[i][1][reg];
            }
        }
        return;
    }

    // ---- fp32 VALU path (unchanged) ----
    int tx = tid & 15, ty = tid >> 4;
    float acc[4][4] = {};
    for (int k0 = 0; k0 < D_IN; k0 += 32) {
        {
            int r = tid >> 2, kq = (tid & 3) * 8;
            size_t base = (size_t)(m0 + r) * D_IN + k0 + kq;
            float4 f0 = *(const float4*)((const float*)xraw + base);
            float4 f1 = *(const float4*)((const float*)xraw + base + 4);
            xs[kq + 0][r] = f0.x; xs[kq + 1][r] = f0.y;
            xs[kq + 2][r] = f0.z; xs[kq + 3][r] = f0.w;
            xs[kq + 4][r] = f1.x; xs[kq + 5][r] = f1.y;
            xs[kq + 6][r] = f1.z; xs[kq + 7][r] = f1.w;
        }
        {
            int kk = tid >> 3, n8 = (tid & 7) * 8;
            size_t base = (size_t)(k0 + kk) * H + n0 + n8;
            float4 f0 = *(const float4*)((const float*)wraw + base);
            float4 f1 = *(const float4*)((const float*)wraw + base + 4);
            ws_[kk][n8+0]=f0.x; ws_[kk][n8+1]=f0.y; ws_[kk][n8+2]=f0.z; ws_[kk][n8+3]=f0.w;
            ws_[kk][n8+4]=f1.x; ws_[kk][n8+5]=f1.y; ws_[kk][n8+6]=f1.z; ws_[kk][n8+7]=f1.w;
        }
        __syncthreads();
        #pragma unroll
        for (int kk = 0; kk < 32; kk++) {
            float4 a4 = *(const float4*)&xs[kk][ty * 4];
            float4 b4 = *(const float4*)&ws_[kk][tx * 4];
            float a[4] = {a4.x, a4.y, a4.z, a4.w};
            float b[4] = {b4.x, b4.y, b4.z, b4.w};
            #pragma unroll
            for (int i = 0; i < 4; i++)
                #pragma unroll
                for (int j = 0; j < 4; j++)
                    acc[i][j] += a[i] * b[j];
        }
        __syncthreads();
    }
    #pragma unroll
    for (int i = 0; i < 4; i++) {
        float4 o = {acc[i][0], acc[i][1], acc[i][2], acc[i][3]};
        *(float4*)&Wh[(size_t)(m0 + ty*4 + i) * H + n0 + tx*4] = o;
    }
}

__global__ __launch_bounds__(256) void k_wh12(
    const float* __restrict__ Wh, const float* __restrict__ a_f,
    float* __restrict__ Wh1, float* __restrict__ Wh2)
{
    int tid = threadIdx.x;
    int wave = tid >> 6, lane = tid & 63;
    int n = blockIdx.x * 4 + wave;
    float4 v  = *(const float4*)(Wh + (size_t)n * H + lane * 4);
    float4 a1 = *(const float4*)(a_f + lane * 4);
    float4 a2 = *(const float4*)(a_f + H + lane * 4);
    float s1 = v.x*a1.x + v.y*a1.y + v.z*a1.z + v.w*a1.w;
    float s2 = v.x*a2.x + v.y*a2.y + v.z*a2.z + v.w*a2.w;
    #pragma unroll
    for (int off = 32; off; off >>= 1) {
        s1 += __shfl_xor(s1, off);
        s2 += __shfl_xor(s2, off);
    }
    if (lane == 0) { Wh1[n] = s1; Wh2[n] = s2; }
}

__global__ __launch_bounds__(256) void k_gat_row(
    const void* __restrict__ adjraw, const int* __restrict__ flag,
    const float* __restrict__ Wh,
    const float* __restrict__ Wh1, const float* __restrict__ Wh2,
    const float* __restrict__ Ca_f, const float* __restrict__ Wg_f,
    float* __restrict__ Gf,
    int* __restrict__ nbr_cnt, u16* __restrict__ nbr_idx,
    void* __restrict__ dout)
{
    const int n = blockIdx.x;
    const int tid = threadIdx.x;
    const int bf = *flag;
    __shared__ int   s_cnt;
    __shared__ int   s_idx[MAXN];
    __shared__ float s_att[MAXN];
    __shared__ float s_z[H];
    __shared__ float s_g[H];
    __shared__ float s_red[256];
    __shared__ float s_sc[16];

    if (tid == 0) s_cnt = 0;
    __syncthreads();

    if (bf) {
        const u16* arow = (const u16*)adjraw + (size_t)n * N_NODES;
        #pragma unroll
        for (int it = 0; it < 4; it++) {
            int base = it * 2048 + tid * 8;
            uint4 raw = *(const uint4*)(arow + base);
            u32 rw[4] = {raw.x, raw.y, raw.z, raw.w};
            #pragma unroll
            for (int q = 0; q < 4; q++) {
                #pragma unroll
                for (int hh = 0; hh < 2; hh++) {
                    u32 u = (rw[q] >> (16 * hh)) & 0xFFFFu;
                    if (__uint_as_float(u << 16) > 0.f) {
                        int p = atomicAdd(&s_cnt, 1);
                        if (p < MAXN) s_idx[p] = base + q * 2 + hh;
                    }
                }
            }
        }
    } else {
        const float* arow = (const float*)adjraw + (size_t)n * N_NODES;
        #pragma unroll
        for (int it = 0; it < 8; it++) {
            int base = it * 1024 + tid * 4;
            float4 v = *(const float4*)(arow + base);
            float vv[4] = {v.x, v.y, v.z, v.w};
            #pragma unroll
            for (int q = 0; q < 4; q++) {
                if (vv[q] > 0.f) {
                    int p = atomicAdd(&s_cnt, 1);
                    if (p < MAXN) s_idx[p] = base + q;
                }
            }
        }
    }
    __syncthreads();
    const int cnt = min(s_cnt, MAXN);
    if (tid == 0) nbr_cnt[n] = cnt;
    if (tid < cnt) nbr_idx[(size_t)n * MAXN + tid] = (u16)s_idx[tid];

    // --- softmax over cnt (<=96) entries: wave shuffle reductions, 3 barriers ---
    float e = 0.f;
    if (tid < cnt) {
        float v = Wh1[n] + Wh2[s_idx[tid]];
        e = v > 0.f ? v : 0.2f * v;
    }
    int lane = tid & 63, wv = tid >> 6;
    float vmax = (tid < cnt) ? e : -3e38f;
    #pragma unroll
    for (int off = 32; off; off >>= 1) vmax = fmaxf(vmax, __shfl_xor(vmax, off));
    if (lane == 0) s_red[wv] = vmax;
    __syncthreads();
    float m = fmaxf(fmaxf(s_red[0], s_red[1]), fmaxf(s_red[2], s_red[3]));
    float wexp = (tid < cnt) ? expf(e - m) : 0.f;
    float ssum = wexp;
    #pragma unroll
    for (int off = 32; off; off >>= 1) ssum += __shfl_xor(ssum, off);
    if (lane == 0) s_red[8 + wv] = ssum;
    __syncthreads();
    float denom = s_red[8] + s_red[9] + s_red[10] + s_red[11];
    if (tid < cnt) s_att[tid] = wexp / denom;
    __syncthreads();

    // --- Z_0 row: att @ Wh, gather unrolled x4 for memory-level parallelism ---
    float acc = 0.f;
    {
        int t = 0;
        for (; t + 4 <= cnt; t += 4) {
            int i0 = s_idx[t], i1 = s_idx[t+1], i2 = s_idx[t+2], i3 = s_idx[t+3];
            float w0 = s_att[t], w1 = s_att[t+1], w2 = s_att[t+2], w3 = s_att[t+3];
            float x0 = Wh[(size_t)i0 * H + tid];
            float x1 = Wh[(size_t)i1 * H + tid];
            float x2 = Wh[(size_t)i2 * H + tid];
            float x3 = Wh[(size_t)i3 * H + tid];
            acc += w0 * x0; acc += w1 * x1; acc += w2 * x2; acc += w3 * x3;
        }
        for (; t < cnt; t++)
            acc += s_att[t] * Wh[(size_t)s_idx[t] * H + tid];
    }
    s_z[tid] = acc;
    store_out(dout, bf, (size_t)Z0_OFF + (size_t)n * H + tid, acc);
    s_g[tid] = acc > 0.f ? acc : expf(acc) - 1.f;
    __syncthreads();

    {
        int k = tid & 15, hb = (tid >> 4) * 16;
        float p = 0.f;
        #pragma unroll
        for (int i = 0; i < 16; i++) {
            float d = s_z[hb + i] - Ca_f[(size_t)k * H + hb + i];
            p += d * d;
        }
        s_red[tid] = p;
    }
    __syncthreads();
    if (tid < 16) {
        float d2 = 0.f;
        #pragma unroll
        for (int q = 0; q < 16; q++) d2 += s_red[q * 16 + tid];
        s_sc[tid] = expf(-sqrtf(d2)) + 1e-10f;
    }
    __syncthreads();
    if (tid < 16) {
        float tot = 0.f;
        #pragma unroll
        for (int q = 0; q < 16; q++) tot += s_sc[q];
        store_out(dout, bf, (size_t)SC_OFF + (size_t)n * K_CL + tid, s_sc[tid] / tot);
    }
    __syncthreads();

    {
        int o = tid & 15, hb = (tid >> 4) * 16;
        float p = 0.f;
        #pragma unroll
        for (int i = 0; i < 16; i++)
            p += s_g[hb + i] * Wg_f[(size_t)(hb + i) * D_OUT + o];
        s_red[tid] = p;
    }
    __syncthreads();
    if (tid < 16) {
        float g2 = 0.f;
        #pragma unroll
        for (int q = 0; q < 16; q++) g2 += s_red[q * 16 + tid];
        Gf[(size_t)n * D_OUT + tid] = g2;
    }
}

__global__ __launch_bounds__(256) void k_f1(
    const int* __restrict__ nbr_cnt, const u16* __restrict__ nbr_idx,
    const float* __restrict__ Gf, const int* __restrict__ flag,
    void* __restrict__ dout)
{
    int tid = threadIdx.x;
    int bf = *flag;
    int r = tid >> 4, o = tid & 15;
    int n = blockIdx.x * 16 + r;
    int cnt = nbr_cnt[n];
    const u16* idx = nbr_idx + (size_t)n * MAXN;
    float acc = 0.f;
    int t = 0;
    for (; t + 4 <= cnt; t += 4) {
        int i0 = idx[t], i1 = idx[t+1], i2 = idx[t+2], i3 = idx[t+3];
        float g0 = Gf[(size_t)i0 * D_OUT + o];
        float g1 = Gf[(size_t)i1 * D_OUT + o];
        float g2 = Gf[(size_t)i2 * D_OUT + o];
        float g3 = Gf[(size_t)i3 * D_OUT + o];
        acc += g0; acc += g1; acc += g2; acc += g3;
    }
    for (; t < cnt; t++)
        acc += Gf[(size_t)idx[t] * D_OUT + o];
    acc = fmaxf(acc, 0.f);
    store_out(dout, bf, (size_t)OUT_OFF + (size_t)n * D_OUT + o, acc);
    store_out(dout, bf, (size_t)Z1_OFF  + (size_t)n * D_OUT + o, acc);
}

extern "C" void kernel_launch(void* const* d_in, const int* in_sizes, int n_in,
                              void* d_out, int out_size, void* d_ws, size_t ws_size,
                              hipStream_t stream) {
    const void* x    = d_in[0];
    const void* adj  = d_in[1];
    const void* C_a  = d_in[2];
    const void* W    = d_in[3];
    const void* av   = d_in[4];
    const void* Wgcn = d_in[5];

    char* wsp = (char*)d_ws;
    int*   flag = (int*)wsp;                   wsp += 256;
    float* Wh   = (float*)wsp;                 wsp += (size_t)N_NODES * H * 4;
    float* Wh1  = (float*)wsp;                 wsp += (size_t)N_NODES * 4;
    float* Wh2  = (float*)wsp;                 wsp += (size_t)N_NODES * 4;
    float* Gf   = (float*)wsp;                 wsp += (size_t)N_NODES * D_OUT * 4;
    int*   ncnt = (int*)wsp;                   wsp += (size_t)N_NODES * 4;
    u16*   nidx = (u16*)wsp;                   wsp += (size_t)N_NODES * MAXN * 2;
    float* a_f  = (float*)wsp;                 wsp += 2 * H * 4;
    float* Ca_f = (float*)wsp;                 wsp += (size_t)K_CL * H * 4;
    float* Wg_f = (float*)wsp;                 wsp += (size_t)H * D_OUT * 4;
    u16*   Wt   = (u16*)wsp;                   wsp += (size_t)H * D_IN * 2;

    hipMemsetAsync(flag, 0, sizeof(int), stream);
    k_detect    <<<256, 256, 0, stream>>>((const u32*)adj, flag);
    k_prep_small<<<34, 256, 0, stream>>>(av, C_a, Wgcn, flag, a_f, Ca_f, Wg_f);
    k_prep_wt   <<<512, 256, 0, stream>>>(W, flag, Wt);
    k_gemm_wh   <<<512, 256, 0, stream>>>(x, W, Wt, flag, Wh);
    k_wh12      <<<N_NODES / 4, 256, 0, stream>>>(Wh, a_f, Wh1, Wh2);
    k_gat_row   <<<N_NODES, 256, 0, stream>>>(adj, flag, Wh, Wh1, Wh2, Ca_f, Wg_f,
                                              Gf, ncnt, nidx, d_out);
    k_f1        <<<N_NODES / 16, 256, 0, stream>>>(ncnt, nidx, Gf, flag, d_out);
}